// Round 4
// baseline (271.434 us; speedup 1.0000x reference)
//
#include <hip/hip_runtime.h>

typedef unsigned short u16;
typedef unsigned int   u32;
typedef __attribute__((ext_vector_type(4))) float f32x4;
typedef __attribute__((ext_vector_type(8))) short s16x8;
typedef __attribute__((ext_vector_type(4))) unsigned short u16x4;
typedef __attribute__((ext_vector_type(8))) unsigned short u16x8;

#define HW    36864
#define NCH   256
#define NB    4
#define NPIX  147456
#define POS   85
#define BN_EPS 1e-5f
#define NBKT  16

// ---- workspace float offsets ----
#define WS_P3      0            // u32-encoded leaf maxes: 4*256*64 = 65536
#define WS_PALL    65536        // 87040
#define WS_YD      152576       // 87040
#define WS_PSUM    239616       // 1024
#define WS_PSQ     240640       // 1024
#define WS_CONTRIB 241664       // 65536
#define WS_FSUMB   307200       // 4096
#define WS_FSQB    311296       // 4096
#define WS_WPK     315392       // u16[65536] = 32768 floats
#define WS_XT      348160       // u16 xT: 18874368 floats
#define WS_YBF     19222528     // u16 y : 18874368 floats
#define WS_TOT1    38096896
#define WS_TOT2    19222528

__device__ __forceinline__ u16 f2bf(float f) {
  u32 u = __builtin_bit_cast(u32, f);
  u += 0x7fffu + ((u >> 16) & 1u);
  return (u16)(u >> 16);
}
__device__ __forceinline__ float bf2f(u16 h) {
  u32 u = ((u32)h) << 16;
  return __builtin_bit_cast(float, u);
}
// monotone float<->u32 encoding for atomicMax
__device__ __forceinline__ u32 encf(float f) {
  u32 b = __builtin_bit_cast(u32, f);
  return (b & 0x80000000u) ? ~b : (b | 0x80000000u);
}
__device__ __forceinline__ float decf(u32 k) {
  u32 b = (k & 0x80000000u) ? (k & 0x7fffffffu) : ~k;
  return __builtin_bit_cast(float, b);
}

// K0: zero accumulators / encoded-max leaves
__global__ __launch_bounds__(256) void k_init(float* __restrict__ wsb) {
  int i = blockIdx.x*256 + threadIdx.x;           // grid 256 -> 65536 threads
  wsb[WS_P3 + i] = 0.f;                           // key 0 == -inf sentinel
  wsb[WS_CONTRIB + i] = 0.f;
  if (i < 2048) wsb[WS_PSUM + i] = 0.f;
  if (i < 8192) wsb[WS_FSUMB + i] = 0.f;
}

// K1: blocks 0..1535: 96px x 256c tile -> xT bf16 + pooled leaf atomicMax
//     blocks 1536..1567: pack wf[:, :256] -> bf16 A-frags
#define LP2 98
__global__ __launch_bounds__(256) void k_prep(const float* __restrict__ x,
                                              const float* __restrict__ wf,
                                              float* __restrict__ wsb) {
  int blk = blockIdx.x;
  int t = threadIdx.x;
  if (blk >= 1536) {
    int fid = (blk - 1536)*256 + t;               // [ks][g][m]
    int m = fid & 255, g = (fid >> 8) & 3, ks = fid >> 10;
    const float* src = wf + (size_t)m*1280 + ks*32 + g*8;
    f32x4 a = *(const f32x4*)src;
    f32x4 c = *(const f32x4*)(src + 4);
    u32* dst = (u32*)((u16*)(wsb + WS_WPK) + (size_t)fid*8);
    dst[0] = (u32)f2bf(a.x) | ((u32)f2bf(a.y) << 16);
    dst[1] = (u32)f2bf(a.z) | ((u32)f2bf(a.w) << 16);
    dst[2] = (u32)f2bf(c.x) | ((u32)f2bf(c.y) << 16);
    dst[3] = (u32)f2bf(c.z) | ((u32)f2bf(c.w) << 16);
    return;
  }
  __shared__ u16 ldsT[256 * LP2];                 // [c][96 px + pad], 50.2 KB
  int b = blk / 384, tile = blk % 384;
  int p0 = tile * 96;
  int r = tile >> 1, half = tile & 1;
  // phase 1: thread t = channel c; read 96 floats, bf16 -> LDS row, 4 cell maxes
  const float* src = x + ((size_t)(b*NCH + t)*HW + p0);
  float cm0 = -3.4e38f, cm1 = -3.4e38f, cm2 = -3.4e38f, cm3 = -3.4e38f;
  #pragma unroll
  for (int q = 0; q < 24; q++) {
    f32x4 v = *(const f32x4*)(src + q*4);
    u16x4 pk;
    pk[0] = f2bf(v.x); pk[1] = f2bf(v.y); pk[2] = f2bf(v.z); pk[3] = f2bf(v.w);
    *(u16x4*)&ldsT[t*LP2 + q*4] = pk;
    float mm = fmaxf(fmaxf(v.x, v.y), fmaxf(v.z, v.w));
    if (q < 6)       cm0 = fmaxf(cm0, mm);
    else if (q < 12) cm1 = fmaxf(cm1, mm);
    else if (q < 18) cm2 = fmaxf(cm2, mm);
    else             cm3 = fmaxf(cm3, mm);
  }
  u32* p3 = (u32*)(wsb + WS_P3) + ((size_t)(b*NCH + t))*64 + (r/24)*8 + half*4;
  atomicMax(&p3[0], encf(cm0));
  atomicMax(&p3[1], encf(cm1));
  atomicMax(&p3[2], encf(cm2));
  atomicMax(&p3[3], encf(cm3));
  __syncthreads();
  // phase 2: 192 threads transpose out: thread = (cg 0..3, px 0..47)
  if (t < 192) {
    int cg = t / 48, pxl = t % 48;
    #pragma unroll
    for (int h = 0; h < 2; h++) {
      int px = h*48 + pxl;
      u16* dst = (u16*)(wsb + WS_XT) + ((size_t)b*HW + p0 + px)*256 + cg*64;
      #pragma unroll
      for (int j8 = 0; j8 < 8; j8++) {
        u16x8 v;
        #pragma unroll
        for (int e = 0; e < 8; e++)
          v[e] = ldsT[(cg*64 + j8*8 + e)*LP2 + px];
        *(u16x8*)(dst + j8*8) = v;
      }
    }
  }
}

// K2: decode leaves -> 85-entry pyramids per (b,c)
__global__ __launch_bounds__(64) void k_ppyr(float* __restrict__ wsb) {
  __shared__ float sm3[64], sm2[16], sm1[4];
  int bc = blockIdx.x;
  int t = threadIdx.x;
  const u32* p3 = (const u32*)(wsb + WS_P3) + (size_t)bc*64;
  float leaf = decf(p3[t]);
  sm3[t] = leaf;
  __syncthreads();
  float* pb = wsb + WS_PALL + (size_t)bc*POS;
  pb[t] = leaf;
  if (t < 16) {
    int i = t >> 2, j = t & 3;
    float m = fmaxf(fmaxf(sm3[(2*i)*8 + 2*j], sm3[(2*i)*8 + 2*j + 1]),
                    fmaxf(sm3[(2*i+1)*8 + 2*j], sm3[(2*i+1)*8 + 2*j + 1]));
    sm2[t] = m; pb[64 + t] = m;
  }
  __syncthreads();
  if (t < 4) {
    int i = t >> 1, j = t & 1;
    float m = fmaxf(fmaxf(sm2[(2*i)*4 + 2*j], sm2[(2*i)*4 + 2*j + 1]),
                    fmaxf(sm2[(2*i+1)*4 + 2*j], sm2[(2*i+1)*4 + 2*j + 1]));
    sm1[t] = m; pb[80 + t] = m;
  }
  __syncthreads();
  if (t == 0)
    pb[84] = fmaxf(fmaxf(sm1[0], sm1[1]), fmaxf(sm1[2], sm1[3]));
}

// K3: pyramid convs on distinct block values + BN stat accumulation
__global__ __launch_bounds__(256) void k_pyr(const float* __restrict__ wconv, float* __restrict__ wsb) {
  __shared__ __align__(16) float pv[256];
  int bi = blockIdx.x;                       // b*85 + pos
  int b = bi / 85, pos = bi % 85;
  int d = (pos < 64) ? 3 : (pos < 80) ? 2 : (pos < 84) ? 1 : 0;
  int t = threadIdx.x;
  pv[t] = wsb[WS_PALL + (size_t)(b*NCH + t)*POS + pos];
  __syncthreads();
  const float* wrow = wconv + ((size_t)d*NCH + t)*NCH;
  float acc = 0.f;
  #pragma unroll 4
  for (int c4 = 0; c4 < 64; c4++) {
    f32x4 wv = *(const f32x4*)(wrow + c4*4);
    f32x4 xv = *(const f32x4*)(&pv[c4*4]);
    acc += wv.x*xv.x + wv.y*xv.y + wv.z*xv.z + wv.w*xv.w;
  }
  wsb[WS_YD + (size_t)(b*NCH + t)*POS + pos] = acc;
  atomicAdd(&wsb[WS_PSUM + d*NCH + t], acc);
  atomicAdd(&wsb[WS_PSQ  + d*NCH + t], acc*acc);
}

// K4: contrib[b][o][cell] += per-depth partial (grid = d*64 + cell)
__global__ __launch_bounds__(256) void k_contrib(const float* __restrict__ wf,
                                                 const float* __restrict__ gs,
                                                 const float* __restrict__ bs,
                                                 float* __restrict__ wsb) {
  __shared__ __align__(16) float pn[4][256];
  int bi = blockIdx.x;
  int d = bi >> 6, cell = bi & 63;
  int by = cell >> 3, bx = cell & 7;
  int t = threadIdx.x;
  int pos = (d == 3) ? cell
          : (d == 2) ? 64 + (by >> 1)*4 + (bx >> 1)
          : (d == 1) ? 80 + (by >> 2)*2 + (bx >> 2)
          : 84;
  float cnt = (float)(4 << (2*d));
  float mu  = wsb[WS_PSUM + d*NCH + t] / cnt;
  float var = wsb[WS_PSQ  + d*NCH + t] / cnt - mu*mu;
  float sc  = gs[d*NCH + t] * rsqrtf(var + BN_EPS);
  float bi_ = bs[d*NCH + t] - mu * sc;
  #pragma unroll
  for (int b = 0; b < 4; b++)
    pn[b][t] = wsb[WS_YD + (size_t)(b*NCH + t)*POS + pos] * sc + bi_;
  __syncthreads();
  const float* wrow = wf + (size_t)t*1280 + 256 + d*256;
  float a0 = 0.f, a1 = 0.f, a2 = 0.f, a3 = 0.f;
  #pragma unroll 4
  for (int j = 0; j < 64; j++) {
    f32x4 wv = *(const f32x4*)(wrow + j*4);
    f32x4 p0 = *(const f32x4*)(&pn[0][j*4]);
    f32x4 p1 = *(const f32x4*)(&pn[1][j*4]);
    f32x4 p2 = *(const f32x4*)(&pn[2][j*4]);
    f32x4 p3 = *(const f32x4*)(&pn[3][j*4]);
    a0 += wv.x*p0.x + wv.y*p0.y + wv.z*p0.z + wv.w*p0.w;
    a1 += wv.x*p1.x + wv.y*p1.y + wv.z*p1.z + wv.w*p1.w;
    a2 += wv.x*p2.x + wv.y*p2.y + wv.z*p2.z + wv.w*p2.w;
    a3 += wv.x*p3.x + wv.y*p3.y + wv.z*p3.z + wv.w*p3.w;
  }
  atomicAdd(&wsb[WS_CONTRIB + (size_t)(0*NCH + t)*64 + cell], a0);
  atomicAdd(&wsb[WS_CONTRIB + (size_t)(1*NCH + t)*64 + cell], a1);
  atomicAdd(&wsb[WS_CONTRIB + (size_t)(2*NCH + t)*64 + cell], a2);
  atomicAdd(&wsb[WS_CONTRIB + (size_t)(3*NCH + t)*64 + cell], a3);
}

// K5: main GEMM, no-LDS MFMA: y[b,o,p] = wfL.x  + contrib; bf16 y + stats
template<bool YBF>
__global__ __launch_bounds__(256, 3) void k_main(float* __restrict__ wsb, float* __restrict__ y) {
  __shared__ float ctile[256*4];
  int wg = blockIdx.x;
  int b = wg / 576, tile = wg % 576;
  int n0 = tile * 64;
  int t = threadIdx.x, w = t >> 6, l = t & 63, g = l >> 4, ln = l & 15;
  int rowblk = (tile/3)/24;
  int cb0 = (tile%3)*64;
  int cblk0 = cb0/24;
  {
    const float* cbase = wsb + WS_CONTRIB + ((size_t)b*NCH + t)*64 + rowblk*8;
    #pragma unroll
    for (int i = 0; i < 4; i++) {
      int cc = cblk0 + i; if (cc > 7) cc = 7;
      ctile[t*4 + i] = cbase[cc];
    }
  }
  __syncthreads();

  const u16* wpk = (const u16*)(wsb + WS_WPK);
  const u16* xT  = (const u16*)(wsb + WS_XT) + (size_t)b*HW*256;
  int mrow = w*64 + ln;
  const u16* xrow = xT + (size_t)(n0 + ln*4)*256 + g*8;

  f32x4 acc[4][4];
  #pragma unroll
  for (int i = 0; i < 4; i++)
    #pragma unroll
    for (int j = 0; j < 4; j++)
      acc[i][j] = {0.f, 0.f, 0.f, 0.f};

  s16x8 a0[4], a1[4], b0[4], b1[4];
  #pragma unroll
  for (int tm = 0; tm < 4; tm++)
    a0[tm] = *(const s16x8*)(wpk + ((size_t)(g)*256 + mrow + tm*16)*8);
  #pragma unroll
  for (int tn = 0; tn < 4; tn++)
    b0[tn] = *(const s16x8*)(xrow + (size_t)tn*256);

  #pragma unroll
  for (int ks = 0; ks < 8; ks++) {
    s16x8 (&af)[4]  = (ks & 1) ? a1 : a0;
    s16x8 (&bf)[4]  = (ks & 1) ? b1 : b0;
    s16x8 (&afn)[4] = (ks & 1) ? a0 : a1;
    s16x8 (&bfn)[4] = (ks & 1) ? b0 : b1;
    if (ks < 7) {
      #pragma unroll
      for (int tm = 0; tm < 4; tm++)
        afn[tm] = *(const s16x8*)(wpk + ((size_t)((ks+1)*4 + g)*256 + mrow + tm*16)*8);
      #pragma unroll
      for (int tn = 0; tn < 4; tn++)
        bfn[tn] = *(const s16x8*)(xrow + (size_t)tn*256 + (ks+1)*32);
    }
    #pragma unroll
    for (int tn = 0; tn < 4; tn++)
      #pragma unroll
      for (int tm = 0; tm < 4; tm++)
        acc[tm][tn] = __builtin_amdgcn_mfma_f32_16x16x32_bf16(af[tm], bf[tn], acc[tm][tn], 0, 0, 0);
  }

  // epilogue
  int ci[4];
  #pragma unroll
  for (int tn = 0; tn < 4; tn++)
    ci[tn] = (cb0 + ln*4 + tn)/24 - cblk0;
  int bkt = wg & (NBKT - 1);
  float* fsum = wsb + WS_FSUMB + bkt*256;
  float* fsq  = wsb + WS_FSQB  + bkt*256;
  u16*   ybb  = (u16*)(wsb + WS_YBF) + (size_t)b*NCH*HW + n0 + ln*4;
  float* yf   = y + (size_t)b*NCH*HW + n0 + ln*4;
  #pragma unroll
  for (int tm = 0; tm < 4; tm++) {
    #pragma unroll
    for (int r = 0; r < 4; r++) {
      int o = w*64 + tm*16 + g*4 + r;
      float v0 = acc[tm][0][r] + ctile[o*4 + ci[0]];
      float v1 = acc[tm][1][r] + ctile[o*4 + ci[1]];
      float v2 = acc[tm][2][r] + ctile[o*4 + ci[2]];
      float v3 = acc[tm][3][r] + ctile[o*4 + ci[3]];
      float s1, s2;
      if (YBF) {
        u16x4 pk;
        pk[0] = f2bf(v0); pk[1] = f2bf(v1); pk[2] = f2bf(v2); pk[3] = f2bf(v3);
        *(u16x4*)(ybb + (size_t)o*HW) = pk;
        float r0 = bf2f(pk[0]), r1 = bf2f(pk[1]), r2 = bf2f(pk[2]), r3 = bf2f(pk[3]);
        s1 = r0 + r1 + r2 + r3;
        s2 = r0*r0 + r1*r1 + r2*r2 + r3*r3;
      } else {
        f32x4 vv = {v0, v1, v2, v3};
        *(f32x4*)(yf + (size_t)o*HW) = vv;
        s1 = v0 + v1 + v2 + v3;
        s2 = v0*v0 + v1*v1 + v2*v2 + v3*v3;
      }
      s1 += __shfl_xor(s1, 1);  s2 += __shfl_xor(s2, 1);
      s1 += __shfl_xor(s1, 2);  s2 += __shfl_xor(s2, 2);
      s1 += __shfl_xor(s1, 4);  s2 += __shfl_xor(s2, 4);
      s1 += __shfl_xor(s1, 8);  s2 += __shfl_xor(s2, 8);
      if (ln == 0) { atomicAdd(&fsum[o], s1); atomicAdd(&fsq[o], s2); }
    }
  }
}

// K6: normalize with inline final BN stats
template<bool YBF>
__global__ __launch_bounds__(256) void k_norm(float* __restrict__ out,
                                              const float* __restrict__ gf,
                                              const float* __restrict__ bfv,
                                              const float* __restrict__ wsb) {
  int bid = blockIdx.x;                      // plane*4 + quarter
  int plane = bid >> 2, q = bid & 3;
  int c = plane & 255;
  float s1 = 0.f, s2 = 0.f;
  #pragma unroll
  for (int i = 0; i < NBKT; i++) {
    s1 += wsb[WS_FSUMB + i*256 + c];
    s2 += wsb[WS_FSQB  + i*256 + c];
  }
  float inv = 1.f / (float)NPIX;
  float mu  = s1 * inv;
  float var = s2 * inv - mu*mu;
  float sc  = gf[c] * rsqrtf(var + BN_EPS);
  float bi  = bfv[c] - mu * sc;
  size_t base4 = ((size_t)plane*HW + q*(HW/4)) >> 2;
  int t = threadIdx.x;
  if (YBF) {
    const u16* yb = (const u16*)(wsb + WS_YBF);
    #pragma unroll
    for (int it = 0; it < 9; it++) {
      size_t i4 = base4 + it*256 + t;
      u16x4 v = *(const u16x4*)(yb + i4*4);
      f32x4 o;
      o.x = bf2f(v[0])*sc + bi;
      o.y = bf2f(v[1])*sc + bi;
      o.z = bf2f(v[2])*sc + bi;
      o.w = bf2f(v[3])*sc + bi;
      ((f32x4*)out)[i4] = o;
    }
  } else {
    #pragma unroll
    for (int it = 0; it < 9; it++) {
      size_t i4 = base4 + it*256 + t;
      f32x4 v = ((f32x4*)out)[i4];
      v.x = v.x*sc + bi; v.y = v.y*sc + bi; v.z = v.z*sc + bi; v.w = v.w*sc + bi;
      ((f32x4*)out)[i4] = v;
    }
  }
}

extern "C" void kernel_launch(void* const* d_in, const int* in_sizes, int n_in,
                              void* d_out, int out_size, void* d_ws, size_t ws_size,
                              hipStream_t stream) {
  const float* x  = (const float*)d_in[0];
  const float* w  = (const float*)d_in[1];
  const float* gs = (const float*)d_in[2];
  const float* bs = (const float*)d_in[3];
  const float* wf = (const float*)d_in[4];
  const float* gf = (const float*)d_in[5];
  const float* bf = (const float*)d_in[6];
  float* y   = (float*)d_out;
  float* wsb = (float*)d_ws;

  bool ybf = ws_size >= (size_t)WS_TOT1 * sizeof(float);

  k_init   <<<256, 256, 0, stream>>>(wsb);
  k_prep   <<<1568, 256, 0, stream>>>(x, wf, wsb);
  k_ppyr   <<<NB*NCH, 64, 0, stream>>>(wsb);
  k_pyr    <<<NB*POS, 256, 0, stream>>>(w, wsb);
  k_contrib<<<256, 256, 0, stream>>>(wf, gs, bs, wsb);
  if (ybf) k_main<true> <<<NB*576, 256, 0, stream>>>(wsb, y);
  else     k_main<false><<<NB*576, 256, 0, stream>>>(wsb, y);
  if (ybf) k_norm<true> <<<4096, 256, 0, stream>>>(y, gf, bf, wsb);
  else     k_norm<false><<<4096, 256, 0, stream>>>(y, gf, bf, wsb);
}

// Round 5
// 219.300 us; speedup vs baseline: 1.2377x; 1.2377x over previous
//
#include <hip/hip_runtime.h>

typedef unsigned short u16;
typedef unsigned int   u32;
typedef __attribute__((ext_vector_type(4))) float f32x4;
typedef __attribute__((ext_vector_type(8))) short s16x8;
typedef __attribute__((ext_vector_type(4))) unsigned short u16x4;
typedef __attribute__((ext_vector_type(8))) unsigned short u16x8;

#define HW    36864
#define NCH   256
#define NB    4
#define NPIX  147456
#define POS   85
#define BN_EPS 1e-5f
#define NBKT  16

// ---- workspace float offsets ----
#define WS_P3      0            // u32-encoded leaf maxes: 4*256*64 = 65536
#define WS_PALL    65536        // 87040
#define WS_YD      152576       // 87040
#define WS_PSUM    239616       // 1024
#define WS_PSQ     240640       // 1024
#define WS_CONTRIB 241664       // 65536
#define WS_FSUMB   307200       // 4096
#define WS_FSQB    311296       // 4096
#define WS_WPK     315392       // u16[65536] = 32768 floats
#define WS_XT      348160       // u16 xT: 18874368 floats
#define WS_YBF     19222528     // u16 y : 18874368 floats
#define WS_TOT1    38096896
#define WS_TOT2    19222528

#define VMCNT(n) asm volatile("s_waitcnt vmcnt(" #n ")" ::: "memory")

__device__ __forceinline__ u16 f2bf(float f) {
  u32 u = __builtin_bit_cast(u32, f);
  u += 0x7fffu + ((u >> 16) & 1u);
  return (u16)(u >> 16);
}
__device__ __forceinline__ float bf2f(u16 h) {
  u32 u = ((u32)h) << 16;
  return __builtin_bit_cast(float, u);
}
// monotone float<->u32 encoding for atomicMax (key 0 == -huge sentinel)
__device__ __forceinline__ u32 encf(float f) {
  u32 b = __builtin_bit_cast(u32, f);
  return (b & 0x80000000u) ? ~b : (b | 0x80000000u);
}
__device__ __forceinline__ float decf(u32 k) {
  u32 b = (k & 0x80000000u) ? (k & 0x7fffffffu) : ~k;
  return __builtin_bit_cast(float, b);
}
__device__ __forceinline__ void gl_lds16(const void* g, void* l) {
  __builtin_amdgcn_global_load_lds(
      (const __attribute__((address_space(1))) u32*)g,
      (__attribute__((address_space(3))) u32*)l, 16, 0, 0);
}

// K0: zero accumulators / encoded-max leaves
__global__ __launch_bounds__(256) void k_init(float* __restrict__ wsb) {
  int i = blockIdx.x*256 + threadIdx.x;           // grid 256 -> 65536 threads
  wsb[WS_P3 + i] = 0.f;
  wsb[WS_CONTRIB + i] = 0.f;
  if (i < 2048) wsb[WS_PSUM + i] = 0.f;
  if (i < 8192) wsb[WS_FSUMB + i] = 0.f;
}

// K1 (k_pp): blocks 0..1535: (b, r, h): 96px x 256ch half-row tile.
//   Coalesced fp32 reads, leaf-pool via shuffle+atomicMax, bf16 LDS transpose
//   (c' = c + 4*px rotation swizzle), coalesced 16B xT writes.
//   blocks 1536..1567: pack wf[:, :256] -> bf16 A-frags.
__global__ __launch_bounds__(256) void k_pp(const float* __restrict__ x,
                                            const float* __restrict__ wf,
                                            float* __restrict__ wsb) {
  int blk = blockIdx.x;
  int t = threadIdx.x;
  if (blk >= 1536) {
    int fid = (blk - 1536)*256 + t;               // [ks32][g][m]
    int m = fid & 255, g = (fid >> 8) & 3, ks = fid >> 10;
    const float* src = wf + (size_t)m*1280 + ks*32 + g*8;
    f32x4 a = *(const f32x4*)src;
    f32x4 c = *(const f32x4*)(src + 4);
    u32* dst = (u32*)((u16*)(wsb + WS_WPK) + (size_t)fid*8);
    dst[0] = (u32)f2bf(a.x) | ((u32)f2bf(a.y) << 16);
    dst[1] = (u32)f2bf(a.z) | ((u32)f2bf(a.w) << 16);
    dst[2] = (u32)f2bf(c.x) | ((u32)f2bf(c.y) << 16);
    dst[3] = (u32)f2bf(c.z) | ((u32)f2bf(c.w) << 16);
    return;
  }
  __shared__ u16 xtile[96*256];                   // [px][c'], 48 KB
  int b = blk / 384, tile = blk % 384;
  int r = tile >> 1, h = tile & 1;
  int p0 = r*192 + h*96;
  int w = t >> 6, l = t & 63;
  int half = l >> 5, lh = l & 31;                 // half selects channel parity
  u32* p3base = (u32*)(wsb + WS_P3);

  // read phase: 32 iters x (4 waves x 2 ch) = 256 channels
  #pragma unroll 2
  for (int i = 0; i < 32; i++) {
    int c = i*8 + w*2 + half;
    const float* src = x + (size_t)(b*NCH + c)*HW + p0 + 3*lh;
    float v0 = src[0], v1 = src[1], v2 = src[2];
    int px0 = 3*lh;
    xtile[(px0    )*256 + ((c + 4* px0     ) & 255)] = f2bf(v0);
    xtile[(px0 + 1)*256 + ((c + 4*(px0 + 1)) & 255)] = f2bf(v1);
    xtile[(px0 + 2)*256 + ((c + 4*(px0 + 2)) & 255)] = f2bf(v2);
    float m3 = fmaxf(v0, fmaxf(v1, v2));
    m3 = fmaxf(m3, __shfl_xor(m3, 1));
    m3 = fmaxf(m3, __shfl_xor(m3, 2));
    m3 = fmaxf(m3, __shfl_xor(m3, 4));
    if ((lh & 7) == 0) {
      int cell = (r/24)*8 + h*4 + (lh >> 3);
      atomicMax(&p3base[(size_t)(b*NCH + c)*64 + cell], encf(m3));
    }
  }
  __syncthreads();
  // write phase: coalesced 16B stores; un-rotate via read offset
  u16* xT = (u16*)(wsb + WS_XT);
  int s = t & 31, pxw = t >> 5;
  #pragma unroll
  for (int j = 0; j < 12; j++) {
    int px = pxw + 8*j;
    int c0 = (s*8 + 4*px) & 255;
    u16x4 q0 = *(const u16x4*)&xtile[px*256 + c0];
    u16x4 q1 = *(const u16x4*)&xtile[px*256 + ((c0 + 4) & 255)];
    u16x8 vv;
    vv[0]=q0[0]; vv[1]=q0[1]; vv[2]=q0[2]; vv[3]=q0[3];
    vv[4]=q1[0]; vv[5]=q1[1]; vv[6]=q1[2]; vv[7]=q1[3];
    *(u16x8*)(xT + ((size_t)b*HW + p0 + px)*256 + s*8) = vv;
  }
}

// K2: decode leaves -> 85-entry pyramids per (b,c)
__global__ __launch_bounds__(64) void k_ppyr(float* __restrict__ wsb) {
  __shared__ float sm3[64], sm2[16], sm1[4];
  int bc = blockIdx.x;
  int t = threadIdx.x;
  const u32* p3 = (const u32*)(wsb + WS_P3) + (size_t)bc*64;
  float leaf = decf(p3[t]);
  sm3[t] = leaf;
  __syncthreads();
  float* pb = wsb + WS_PALL + (size_t)bc*POS;
  pb[t] = leaf;
  if (t < 16) {
    int i = t >> 2, j = t & 3;
    float m = fmaxf(fmaxf(sm3[(2*i)*8 + 2*j], sm3[(2*i)*8 + 2*j + 1]),
                    fmaxf(sm3[(2*i+1)*8 + 2*j], sm3[(2*i+1)*8 + 2*j + 1]));
    sm2[t] = m; pb[64 + t] = m;
  }
  __syncthreads();
  if (t < 4) {
    int i = t >> 1, j = t & 1;
    float m = fmaxf(fmaxf(sm2[(2*i)*4 + 2*j], sm2[(2*i)*4 + 2*j + 1]),
                    fmaxf(sm2[(2*i+1)*4 + 2*j], sm2[(2*i+1)*4 + 2*j + 1]));
    sm1[t] = m; pb[80 + t] = m;
  }
  __syncthreads();
  if (t == 0)
    pb[84] = fmaxf(fmaxf(sm1[0], sm1[1]), fmaxf(sm1[2], sm1[3]));
}

// K3: pyramid convs on distinct block values + BN stat accumulation
__global__ __launch_bounds__(256) void k_pyr(const float* __restrict__ wconv, float* __restrict__ wsb) {
  __shared__ __align__(16) float pv[256];
  int bi = blockIdx.x;                       // b*85 + pos
  int b = bi / 85, pos = bi % 85;
  int d = (pos < 64) ? 3 : (pos < 80) ? 2 : (pos < 84) ? 1 : 0;
  int t = threadIdx.x;
  pv[t] = wsb[WS_PALL + (size_t)(b*NCH + t)*POS + pos];
  __syncthreads();
  const float* wrow = wconv + ((size_t)d*NCH + t)*NCH;
  float acc = 0.f;
  #pragma unroll 4
  for (int c4 = 0; c4 < 64; c4++) {
    f32x4 wv = *(const f32x4*)(wrow + c4*4);
    f32x4 xv = *(const f32x4*)(&pv[c4*4]);
    acc += wv.x*xv.x + wv.y*xv.y + wv.z*xv.z + wv.w*xv.w;
  }
  wsb[WS_YD + (size_t)(b*NCH + t)*POS + pos] = acc;
  atomicAdd(&wsb[WS_PSUM + d*NCH + t], acc);
  atomicAdd(&wsb[WS_PSQ  + d*NCH + t], acc*acc);
}

// K4: contrib[b][o][cell] += per-depth partial (grid = d*64 + cell)
__global__ __launch_bounds__(256) void k_contrib(const float* __restrict__ wf,
                                                 const float* __restrict__ gs,
                                                 const float* __restrict__ bs,
                                                 float* __restrict__ wsb) {
  __shared__ __align__(16) float pn[4][256];
  int bi = blockIdx.x;
  int d = bi >> 6, cell = bi & 63;
  int by = cell >> 3, bx = cell & 7;
  int t = threadIdx.x;
  int pos = (d == 3) ? cell
          : (d == 2) ? 64 + (by >> 1)*4 + (bx >> 1)
          : (d == 1) ? 80 + (by >> 2)*2 + (bx >> 2)
          : 84;
  float cnt = (float)(4 << (2*d));
  float mu  = wsb[WS_PSUM + d*NCH + t] / cnt;
  float var = wsb[WS_PSQ  + d*NCH + t] / cnt - mu*mu;
  float sc  = gs[d*NCH + t] * rsqrtf(var + BN_EPS);
  float bi_ = bs[d*NCH + t] - mu * sc;
  #pragma unroll
  for (int b = 0; b < 4; b++)
    pn[b][t] = wsb[WS_YD + (size_t)(b*NCH + t)*POS + pos] * sc + bi_;
  __syncthreads();
  const float* wrow = wf + (size_t)t*1280 + 256 + d*256;
  float a0 = 0.f, a1 = 0.f, a2 = 0.f, a3 = 0.f;
  #pragma unroll 4
  for (int j = 0; j < 64; j++) {
    f32x4 wv = *(const f32x4*)(wrow + j*4);
    f32x4 p0 = *(const f32x4*)(&pn[0][j*4]);
    f32x4 p1 = *(const f32x4*)(&pn[1][j*4]);
    f32x4 p2 = *(const f32x4*)(&pn[2][j*4]);
    f32x4 p3 = *(const f32x4*)(&pn[3][j*4]);
    a0 += wv.x*p0.x + wv.y*p0.y + wv.z*p0.z + wv.w*p0.w;
    a1 += wv.x*p1.x + wv.y*p1.y + wv.z*p1.z + wv.w*p1.w;
    a2 += wv.x*p2.x + wv.y*p2.y + wv.z*p2.z + wv.w*p2.w;
    a3 += wv.x*p3.x + wv.y*p3.y + wv.z*p3.z + wv.w*p3.w;
  }
  atomicAdd(&wsb[WS_CONTRIB + (size_t)(0*NCH + t)*64 + cell], a0);
  atomicAdd(&wsb[WS_CONTRIB + (size_t)(1*NCH + t)*64 + cell], a1);
  atomicAdd(&wsb[WS_CONTRIB + (size_t)(2*NCH + t)*64 + cell], a2);
  atomicAdd(&wsb[WS_CONTRIB + (size_t)(3*NCH + t)*64 + cell], a3);
}

// K5: main GEMM. BK=64 slabs, 3-buffer gl_lds staging, counted vmcnt + raw
// s_barrier (never vmcnt(0) mid-loop). XOR-swizzled LDS slots. Coalesced epilogue.
template<bool YBF>
__global__ __launch_bounds__(256, 3) void k_main(float* __restrict__ wsb, float* __restrict__ y) {
  __shared__ __align__(16) u16 xbuf[3*4096];      // 3 slabs x [64px][8 slots x 8ch] = 24 KB
  __shared__ float ctile[256*4];                  // 4 KB
  int wg = blockIdx.x;
  int b = wg / 576, tile = wg % 576;
  int n0 = tile * 64;
  int t = threadIdx.x, w = t >> 6, l = t & 63, g = l >> 4, ln = l & 15;
  int rowblk = (tile/3)/24;
  int cb0 = (tile%3)*64;
  int cblk0 = cb0/24;
  {
    const float* cbase = wsb + WS_CONTRIB + ((size_t)b*NCH + t)*64 + rowblk*8;
    #pragma unroll
    for (int i = 0; i < 4; i++) {
      int cc = cblk0 + i; if (cc > 7) cc = 7;
      ctile[t*4 + i] = cbase[cc];
    }
  }
  __syncthreads();                                // drains ctile writes; nothing else outstanding

  const u16* wpk = (const u16*)(wsb + WS_WPK);
  const u16* xT  = (const u16*)(wsb + WS_XT) + (size_t)b*HW*256;
  int mrow = w*64 + ln;
  // staging map: linear slot L=t (and t+256): px=L>>3, s=(L&7)^((L>>5)&7)
  int ssw = (t & 7) ^ ((t >> 5) & 7);
  const u16* srcb = xT + (size_t)(n0 + (t >> 3))*256 + ssw*8;
  u16* dstb = xbuf + t*8;

  f32x4 acc[4][4];
  #pragma unroll
  for (int i = 0; i < 4; i++)
    #pragma unroll
    for (int j = 0; j < 4; j++)
      acc[i][j] = {0.f, 0.f, 0.f, 0.f};

  #define STAGE(slab) do {                                   \
    const u16* s1 = srcb + (slab)*64;                        \
    u16* d1 = dstb + ((slab)%3)*4096;                        \
    gl_lds16(s1, d1);                                        \
    gl_lds16(s1 + 8192, d1 + 2048);                          \
  } while (0)

  #define COMPUTE(slab) do {                                             \
    const u16* xb = xbuf + ((slab)%3)*4096;                              \
    _Pragma("unroll")                                                    \
    for (int ksub = 0; ksub < 2; ksub++) {                               \
      int ks32 = (slab)*2 + ksub;                                        \
      s16x8 af[4];                                                       \
      _Pragma("unroll")                                                  \
      for (int tm = 0; tm < 4; tm++)                                     \
        af[tm] = *(const s16x8*)(wpk + ((size_t)(ks32*4 + g)*256 + mrow + tm*16)*8); \
      _Pragma("unroll")                                                  \
      for (int tn = 0; tn < 4; tn++) {                                   \
        int px = ln*4 + tn;                                              \
        int sl = (ksub*4 + g) ^ (ln & 7);                                \
        s16x8 bfr = *(const s16x8*)(xb + px*64 + sl*8);                  \
        _Pragma("unroll")                                                \
        for (int tm = 0; tm < 4; tm++)                                   \
          acc[tm][tn] = __builtin_amdgcn_mfma_f32_16x16x32_bf16(af[tm], bfr, acc[tm][tn], 0, 0, 0); \
      }                                                                  \
    }                                                                    \
  } while (0)

  STAGE(0); STAGE(1);
  VMCNT(2); __builtin_amdgcn_s_barrier();
  COMPUTE(0); STAGE(2);
  VMCNT(2); __builtin_amdgcn_s_barrier();
  COMPUTE(1); STAGE(3);
  VMCNT(2); __builtin_amdgcn_s_barrier();
  COMPUTE(2);
  VMCNT(0); __builtin_amdgcn_s_barrier();
  COMPUTE(3);
  #undef STAGE
  #undef COMPUTE

  // epilogue: add contrib, store y (coalesced u16x4 per lane), channel stats
  int ci[4];
  #pragma unroll
  for (int tn = 0; tn < 4; tn++)
    ci[tn] = (cb0 + ln*4 + tn)/24 - cblk0;
  int bkt = wg & (NBKT - 1);
  float* fsum = wsb + WS_FSUMB + bkt*256;
  float* fsq  = wsb + WS_FSQB  + bkt*256;
  u16*   ybb  = (u16*)(wsb + WS_YBF) + (size_t)b*NCH*HW + n0 + ln*4;
  float* yf   = y + (size_t)b*NCH*HW + n0 + ln*4;
  #pragma unroll
  for (int tm = 0; tm < 4; tm++) {
    #pragma unroll
    for (int r = 0; r < 4; r++) {
      int o = w*64 + tm*16 + g*4 + r;
      float v0 = acc[tm][0][r] + ctile[o*4 + ci[0]];
      float v1 = acc[tm][1][r] + ctile[o*4 + ci[1]];
      float v2 = acc[tm][2][r] + ctile[o*4 + ci[2]];
      float v3 = acc[tm][3][r] + ctile[o*4 + ci[3]];
      float s1, s2;
      if (YBF) {
        u16x4 pk;
        pk[0] = f2bf(v0); pk[1] = f2bf(v1); pk[2] = f2bf(v2); pk[3] = f2bf(v3);
        *(u16x4*)(ybb + (size_t)o*HW) = pk;
        float r0 = bf2f(pk[0]), r1 = bf2f(pk[1]), r2 = bf2f(pk[2]), r3 = bf2f(pk[3]);
        s1 = r0 + r1 + r2 + r3;
        s2 = r0*r0 + r1*r1 + r2*r2 + r3*r3;
      } else {
        f32x4 vv = {v0, v1, v2, v3};
        *(f32x4*)(yf + (size_t)o*HW) = vv;
        s1 = v0 + v1 + v2 + v3;
        s2 = v0*v0 + v1*v1 + v2*v2 + v3*v3;
      }
      s1 += __shfl_xor(s1, 1);  s2 += __shfl_xor(s2, 1);
      s1 += __shfl_xor(s1, 2);  s2 += __shfl_xor(s2, 2);
      s1 += __shfl_xor(s1, 4);  s2 += __shfl_xor(s2, 4);
      s1 += __shfl_xor(s1, 8);  s2 += __shfl_xor(s2, 8);
      if (ln == 0) { atomicAdd(&fsum[o], s1); atomicAdd(&fsq[o], s2); }
    }
  }
}

// K6: normalize with inline final BN stats
template<bool YBF>
__global__ __launch_bounds__(256) void k_norm(float* __restrict__ out,
                                              const float* __restrict__ gf,
                                              const float* __restrict__ bfv,
                                              const float* __restrict__ wsb) {
  int bid = blockIdx.x;                      // plane*4 + quarter
  int plane = bid >> 2, q = bid & 3;
  int c = plane & 255;
  float s1 = 0.f, s2 = 0.f;
  #pragma unroll
  for (int i = 0; i < NBKT; i++) {
    s1 += wsb[WS_FSUMB + i*256 + c];
    s2 += wsb[WS_FSQB  + i*256 + c];
  }
  float inv = 1.f / (float)NPIX;
  float mu  = s1 * inv;
  float var = s2 * inv - mu*mu;
  float sc  = gf[c] * rsqrtf(var + BN_EPS);
  float bi  = bfv[c] - mu * sc;
  size_t base4 = ((size_t)plane*HW + q*(HW/4)) >> 2;
  int t = threadIdx.x;
  if (YBF) {
    const u16* yb = (const u16*)(wsb + WS_YBF);
    #pragma unroll
    for (int it = 0; it < 9; it++) {
      size_t i4 = base4 + it*256 + t;
      u16x4 v = *(const u16x4*)(yb + i4*4);
      f32x4 o;
      o.x = bf2f(v[0])*sc + bi;
      o.y = bf2f(v[1])*sc + bi;
      o.z = bf2f(v[2])*sc + bi;
      o.w = bf2f(v[3])*sc + bi;
      ((f32x4*)out)[i4] = o;
    }
  } else {
    #pragma unroll
    for (int it = 0; it < 9; it++) {
      size_t i4 = base4 + it*256 + t;
      f32x4 v = ((f32x4*)out)[i4];
      v.x = v.x*sc + bi; v.y = v.y*sc + bi; v.z = v.z*sc + bi; v.w = v.w*sc + bi;
      ((f32x4*)out)[i4] = v;
    }
  }
}

extern "C" void kernel_launch(void* const* d_in, const int* in_sizes, int n_in,
                              void* d_out, int out_size, void* d_ws, size_t ws_size,
                              hipStream_t stream) {
  const float* x  = (const float*)d_in[0];
  const float* w  = (const float*)d_in[1];
  const float* gs = (const float*)d_in[2];
  const float* bs = (const float*)d_in[3];
  const float* wf = (const float*)d_in[4];
  const float* gf = (const float*)d_in[5];
  const float* bf = (const float*)d_in[6];
  float* y   = (float*)d_out;
  float* wsb = (float*)d_ws;

  bool ybf = ws_size >= (size_t)WS_TOT1 * sizeof(float);

  k_init   <<<256, 256, 0, stream>>>(wsb);
  k_pp     <<<1568, 256, 0, stream>>>(x, wf, wsb);
  k_ppyr   <<<NB*NCH, 64, 0, stream>>>(wsb);
  k_pyr    <<<NB*POS, 256, 0, stream>>>(w, wsb);
  k_contrib<<<256, 256, 0, stream>>>(wf, gs, bs, wsb);
  if (ybf) k_main<true> <<<NB*576, 256, 0, stream>>>(wsb, y);
  else     k_main<false><<<NB*576, 256, 0, stream>>>(wsb, y);
  if (ybf) k_norm<true> <<<4096, 256, 0, stream>>>(y, gf, bf, wsb);
  else     k_norm<false><<<4096, 256, 0, stream>>>(y, gf, bf, wsb);
}

// Round 6
// 213.301 us; speedup vs baseline: 1.2725x; 1.0281x over previous
//
#include <hip/hip_runtime.h>

typedef unsigned short u16;
typedef unsigned int   u32;
typedef __attribute__((ext_vector_type(4))) float f32x4;
typedef __attribute__((ext_vector_type(8))) short s16x8;
typedef __attribute__((ext_vector_type(4))) unsigned short u16x4;
typedef __attribute__((ext_vector_type(8))) unsigned short u16x8;

#define HW    36864
#define NCH   256
#define NB    4
#define NPIX  147456
#define POS   85
#define BN_EPS 1e-5f
#define NBKT  16

// ---- workspace float offsets ----
#define WS_PALL    0            // 4*256*85 = 87040
#define WS_YD      87040        // 87040
#define WS_PSUM    174080       // 1024
#define WS_PSQ     175104       // 1024
#define WS_CONTRIB 176128       // 65536 (non-atomic now, no zeroing needed)
#define WS_FSUMB   241664       // 4096
#define WS_FSQB    245760       // 4096
#define WS_WPK     249856       // u16[65536] = 32768 floats
#define WS_YBF     282624       // u16 y: 18874368 floats
#define WS_TOT1    (WS_YBF + NB*NCH*HW/2)

__device__ __forceinline__ u16 f2bf(float f) {
  u32 u = __builtin_bit_cast(u32, f);
  u += 0x7fffu + ((u >> 16) & 1u);
  return (u16)(u >> 16);
}
__device__ __forceinline__ float bf2f(u16 h) {
  u32 u = ((u32)h) << 16;
  return __builtin_bit_cast(float, u);
}

// K1: per-(b,c) plane -> 85-entry block-max pyramid (proven round-2 kernel)
__global__ __launch_bounds__(192) void k_pool(const float* __restrict__ x, float* __restrict__ wsb) {
  __shared__ float sm[8][4][48];
  __shared__ float sp[84];
  int bc = blockIdx.x;                       // b*256 + c
  const float* base = x + (size_t)bc * HW;
  int t = threadIdx.x;
  int cg = t % 48, rg = t / 48;
  if (bc == 0) {                             // zero stat accumulators
    for (int i = t; i < 2048; i += 192) wsb[WS_PSUM + i] = 0.f;
    for (int i = t; i < 8192; i += 192) wsb[WS_FSUMB + i] = 0.f;
  }
  #pragma unroll
  for (int byi = 0; byi < 8; byi++) {
    float mm = -3.4e38f;
    #pragma unroll
    for (int rr = 0; rr < 6; rr++) {
      int r = byi*24 + rg + 4*rr;
      f32x4 v = *(const f32x4*)(base + r*192 + cg*4);
      mm = fmaxf(mm, fmaxf(fmaxf(v.x, v.y), fmaxf(v.z, v.w)));
    }
    sm[byi][rg][cg] = mm;
  }
  __syncthreads();
  size_t pb = WS_PALL + (size_t)bc * POS;
  if (t < 64) {
    int by = t >> 3, bx = t & 7;
    float mm = -3.4e38f;
    for (int r2 = 0; r2 < 4; r2++)
      for (int cq = 0; cq < 6; cq++)
        mm = fmaxf(mm, sm[by][r2][bx*6 + cq]);
    sp[t] = mm;
    wsb[pb + t] = mm;
  }
  __syncthreads();
  if (t < 16) {
    int i = t >> 2, j = t & 3;
    float mm = fmaxf(fmaxf(sp[(2*i)*8 + 2*j], sp[(2*i)*8 + 2*j + 1]),
                     fmaxf(sp[(2*i+1)*8 + 2*j], sp[(2*i+1)*8 + 2*j + 1]));
    sp[64 + t] = mm;
    wsb[pb + 64 + t] = mm;
  }
  __syncthreads();
  if (t < 4) {
    int i = t >> 1, j = t & 1;
    float mm = fmaxf(fmaxf(sp[64 + (2*i)*4 + 2*j], sp[64 + (2*i)*4 + 2*j + 1]),
                     fmaxf(sp[64 + (2*i+1)*4 + 2*j], sp[64 + (2*i+1)*4 + 2*j + 1]));
    sp[80 + t] = mm;
    wsb[pb + 80 + t] = mm;
  }
  __syncthreads();
  if (t == 0)
    wsb[pb + 84] = fmaxf(fmaxf(sp[80], sp[81]), fmaxf(sp[82], sp[83]));
}

// K1b: pack wf[:, :256] -> bf16 A-frags wpk[((ks*4+g)*256 + m)*8 + j]
__global__ __launch_bounds__(256) void k_wpack(const float* __restrict__ wf, float* __restrict__ wsb) {
  int fid = blockIdx.x*256 + threadIdx.x;    // 0..8191
  int m = fid & 255, g = (fid >> 8) & 3, ks = fid >> 10;
  const float* src = wf + (size_t)m*1280 + ks*32 + g*8;
  f32x4 a = *(const f32x4*)src;
  f32x4 c = *(const f32x4*)(src + 4);
  u32* dst = (u32*)((u16*)(wsb + WS_WPK) + (size_t)fid*8);
  dst[0] = (u32)f2bf(a.x) | ((u32)f2bf(a.y) << 16);
  dst[1] = (u32)f2bf(a.z) | ((u32)f2bf(a.w) << 16);
  dst[2] = (u32)f2bf(c.x) | ((u32)f2bf(c.y) << 16);
  dst[3] = (u32)f2bf(c.z) | ((u32)f2bf(c.w) << 16);
}

// K2: pyramid convs on distinct block values + BN stat accumulation
__global__ __launch_bounds__(256) void k_pyr(const float* __restrict__ wconv, float* __restrict__ wsb) {
  __shared__ __align__(16) float pv[256];
  int bi = blockIdx.x;                       // b*85 + pos
  int b = bi / 85, pos = bi % 85;
  int d = (pos < 64) ? 3 : (pos < 80) ? 2 : (pos < 84) ? 1 : 0;
  int t = threadIdx.x;
  pv[t] = wsb[WS_PALL + (size_t)(b*NCH + t)*POS + pos];
  __syncthreads();
  const float* wrow = wconv + ((size_t)d*NCH + t)*NCH;
  float acc = 0.f;
  #pragma unroll 4
  for (int c4 = 0; c4 < 64; c4++) {
    f32x4 wv = *(const f32x4*)(wrow + c4*4);
    f32x4 xv = *(const f32x4*)(&pv[c4*4]);
    acc += wv.x*xv.x + wv.y*xv.y + wv.z*xv.z + wv.w*xv.w;
  }
  wsb[WS_YD + (size_t)(b*NCH + t)*POS + pos] = acc;
  atomicAdd(&wsb[WS_PSUM + d*NCH + t], acc);
  atomicAdd(&wsb[WS_PSQ  + d*NCH + t], acc*acc);
}

// K3: contrib[b][o][cell] = sum over all 4 depths (no atomics; grid = 64 cells)
__global__ __launch_bounds__(256) void k_contrib(const float* __restrict__ wf,
                                                 const float* __restrict__ gs,
                                                 const float* __restrict__ bs,
                                                 float* __restrict__ wsb) {
  __shared__ __align__(16) float pn[16][256];   // [d*4+b][c]
  int cell = blockIdx.x;
  int by = cell >> 3, bx = cell & 7;
  int t = threadIdx.x;
  #pragma unroll
  for (int d = 0; d < 4; d++) {
    int pos = (d == 3) ? cell
            : (d == 2) ? 64 + (by >> 1)*4 + (bx >> 1)
            : (d == 1) ? 80 + (by >> 2)*2 + (bx >> 2)
            : 84;
    float cnt = (float)(4 << (2*d));
    float mu  = wsb[WS_PSUM + d*NCH + t] / cnt;
    float var = wsb[WS_PSQ  + d*NCH + t] / cnt - mu*mu;
    float sc  = gs[d*NCH + t] * rsqrtf(var + BN_EPS);
    float bi_ = bs[d*NCH + t] - mu * sc;
    #pragma unroll
    for (int b = 0; b < 4; b++)
      pn[d*4 + b][t] = wsb[WS_YD + (size_t)(b*NCH + t)*POS + pos] * sc + bi_;
  }
  __syncthreads();
  float a0 = 0.f, a1 = 0.f, a2 = 0.f, a3 = 0.f;
  #pragma unroll
  for (int d = 0; d < 4; d++) {
    const float* wrow = wf + (size_t)t*1280 + 256 + d*256;
    #pragma unroll 4
    for (int j = 0; j < 64; j++) {
      f32x4 wv = *(const f32x4*)(wrow + j*4);
      f32x4 p0 = *(const f32x4*)(&pn[d*4 + 0][j*4]);
      f32x4 p1 = *(const f32x4*)(&pn[d*4 + 1][j*4]);
      f32x4 p2 = *(const f32x4*)(&pn[d*4 + 2][j*4]);
      f32x4 p3 = *(const f32x4*)(&pn[d*4 + 3][j*4]);
      a0 += wv.x*p0.x + wv.y*p0.y + wv.z*p0.z + wv.w*p0.w;
      a1 += wv.x*p1.x + wv.y*p1.y + wv.z*p1.z + wv.w*p1.w;
      a2 += wv.x*p2.x + wv.y*p2.y + wv.z*p2.z + wv.w*p2.w;
      a3 += wv.x*p3.x + wv.y*p3.y + wv.z*p3.z + wv.w*p3.w;
    }
  }
  wsb[WS_CONTRIB + (size_t)(0*NCH + t)*64 + cell] = a0;
  wsb[WS_CONTRIB + (size_t)(1*NCH + t)*64 + cell] = a1;
  wsb[WS_CONTRIB + (size_t)(2*NCH + t)*64 + cell] = a2;
  wsb[WS_CONTRIB + (size_t)(3*NCH + t)*64 + cell] = a3;
}

// K4: main GEMM, reg-staged transpose direct from planar fp32 x.
//   4-slab-deep global prefetch (counted vmcnt by compiler), raw s_barrier +
//   lgkmcnt(0) only (never drains the x-load queue), double-buffered LDS with
//   group-XOR swizzle, double-buffered W-frags. Epilogue: contrib + bf16 y + stats.
template<bool YBF>
__global__ __launch_bounds__(256, 3) void k_main(const float* __restrict__ x,
                                                 float* __restrict__ wsb, float* __restrict__ y) {
  __shared__ __align__(16) u32 xbuf[2][64*20];   // [buf][px*20 dw], 80B pitch, 10 KB
  __shared__ float ctile[256*4];                 // 4 KB
  int wg = blockIdx.x;
  int b = wg / 576, tile = wg % 576;
  int n0 = tile * 64;
  int t = threadIdx.x, w = t >> 6, l = t & 63, g = l >> 4, ln = l & 15;
  int cb0 = (tile % 3) * 64;
  int rowblk = (tile / 3) / 24;
  int cblk0 = cb0 / 24;
  const u16* wpk = (const u16*)(wsb + WS_WPK);
  int mrow = w*64 + ln;
  int qq = t & 15, c2 = t >> 4;                  // staging: px-quad, channel-pair
  const float* xsrc = x + (size_t)(b*NCH + 2*c2)*HW + n0 + 4*qq;

  // ctile global loads (issued first)
  float ct[4];
  {
    const float* cbase = wsb + WS_CONTRIB + ((size_t)b*NCH + t)*64 + rowblk*8;
    #pragma unroll
    for (int i = 0; i < 4; i++) {
      int cc = cblk0 + i; if (cc > 7) cc = 7;
      ct[i] = cbase[cc];
    }
  }
  // prologue: x loads slabs 0..3 (8 loads in flight)
  f32x4 xa[4], xbv[4];
  #pragma unroll
  for (int i = 0; i < 4; i++) {
    xa[i]  = *(const f32x4*)(xsrc + (size_t)(i*32)*HW);
    xbv[i] = *(const f32x4*)(xsrc + (size_t)(i*32 + 1)*HW);
  }
  // W-frag double buffer; prefetch slab 0
  s16x8 af[2][4];
  #pragma unroll
  for (int tm = 0; tm < 4; tm++)
    af[0][tm] = *(const s16x8*)(wpk + ((size_t)g*256 + mrow + tm*16)*8);

  #pragma unroll
  for (int i = 0; i < 4; i++) ctile[t*4 + i] = ct[i];
  asm volatile("s_waitcnt lgkmcnt(0)" ::: "memory");
  __builtin_amdgcn_s_barrier();
  __builtin_amdgcn_sched_barrier(0);

  f32x4 acc[4][4];
  #pragma unroll
  for (int i = 0; i < 4; i++)
    #pragma unroll
    for (int j = 0; j < 4; j++)
      acc[i][j] = {0.f, 0.f, 0.f, 0.f};

  int slot = (((c2 >> 2) ^ (qq & 3)) << 2) | (c2 & 3);   // group-XOR swizzle

  #pragma unroll
  for (int i = 0; i < 8; i++) {
    // stage slab i: compiler emits COUNTED vmcnt for xa/xbv[i&3] (newer loads stay in flight)
    {
      u32* dst = &xbuf[i & 1][0];
      f32x4 va = xa[i & 3], vb = xbv[i & 3];
      #pragma unroll
      for (int j = 0; j < 4; j++) {
        u32 pk = (u32)f2bf(va[j]) | ((u32)f2bf(vb[j]) << 16);
        dst[(4*qq + j)*20 + slot] = pk;
      }
    }
    asm volatile("s_waitcnt lgkmcnt(0)" ::: "memory");
    __builtin_amdgcn_s_barrier();
    __builtin_amdgcn_sched_barrier(0);
    // prefetch x slab i+4
    if (i < 4) {
      xa[i & 3]  = *(const f32x4*)(xsrc + (size_t)((i+4)*32)*HW);
      xbv[i & 3] = *(const f32x4*)(xsrc + (size_t)((i+4)*32 + 1)*HW);
    }
    // prefetch W-frags slab i+1
    if (i < 7) {
      #pragma unroll
      for (int tm = 0; tm < 4; tm++)
        af[(i+1) & 1][tm] = *(const s16x8*)(wpk + ((size_t)((i+1)*4 + g)*256 + mrow + tm*16)*8);
    }
    // compute slab i
    #pragma unroll
    for (int tn = 0; tn < 4; tn++) {
      int px = 16*tn + ln;
      int gr = g ^ ((px >> 2) & 3);
      s16x8 bfr = *(const s16x8*)((const u16*)&xbuf[i & 1][px*20 + gr*4]);
      #pragma unroll
      for (int tm = 0; tm < 4; tm++)
        acc[tm][tn] = __builtin_amdgcn_mfma_f32_16x16x32_bf16(af[i & 1][tm], bfr, acc[tm][tn], 0, 0, 0);
    }
  }

  // epilogue: add contrib, store y, accumulate channel stats
  int ci[4];
  #pragma unroll
  for (int tn = 0; tn < 4; tn++)
    ci[tn] = (cb0 + 16*tn + ln)/24 - cblk0;
  int bkt = wg & (NBKT - 1);
  float* fsum = wsb + WS_FSUMB + bkt*256;
  float* fsq  = wsb + WS_FSQB  + bkt*256;
  u16*   ybb  = (u16*)(wsb + WS_YBF) + (size_t)b*NCH*HW + n0;
  float* yf   = y + (size_t)b*NCH*HW + n0;
  #pragma unroll
  for (int tm = 0; tm < 4; tm++) {
    #pragma unroll
    for (int r = 0; r < 4; r++) {
      int o = w*64 + tm*16 + g*4 + r;
      float s1 = 0.f, s2 = 0.f;
      #pragma unroll
      for (int tn = 0; tn < 4; tn++) {
        int px = 16*tn + ln;
        float v = acc[tm][tn][r] + ctile[o*4 + ci[tn]];
        if (YBF) {
          u16 h = f2bf(v);
          ybb[(size_t)o*HW + px] = h;
          float yr = bf2f(h);
          s1 += yr; s2 += yr*yr;
        } else {
          yf[(size_t)o*HW + px] = v;
          s1 += v; s2 += v*v;
        }
      }
      s1 += __shfl_xor(s1, 1);  s2 += __shfl_xor(s2, 1);
      s1 += __shfl_xor(s1, 2);  s2 += __shfl_xor(s2, 2);
      s1 += __shfl_xor(s1, 4);  s2 += __shfl_xor(s2, 4);
      s1 += __shfl_xor(s1, 8);  s2 += __shfl_xor(s2, 8);
      if (ln == 0) { atomicAdd(&fsum[o], s1); atomicAdd(&fsq[o], s2); }
    }
  }
}

// K5: normalize with inline final BN stats
template<bool YBF>
__global__ __launch_bounds__(256) void k_norm(float* __restrict__ out,
                                              const float* __restrict__ gf,
                                              const float* __restrict__ bfv,
                                              const float* __restrict__ wsb) {
  int bid = blockIdx.x;
  int t = threadIdx.x;
  if (YBF) {
    int plane = bid >> 1, hf = bid & 1;        // grid 2048
    int c = plane & 255;
    float s1 = 0.f, s2 = 0.f;
    #pragma unroll
    for (int i = 0; i < NBKT; i++) {
      s1 += wsb[WS_FSUMB + i*256 + c];
      s2 += wsb[WS_FSQB  + i*256 + c];
    }
    float inv = 1.f / (float)NPIX;
    float mu  = s1 * inv;
    float var = s2 * inv - mu*mu;
    float sc  = gf[c] * rsqrtf(var + BN_EPS);
    float bi  = bfv[c] - mu * sc;
    const u16* yb = (const u16*)(wsb + WS_YBF);
    size_t gbase = (size_t)plane*4608 + hf*2304;   // u16x8 groups
    #pragma unroll
    for (int it = 0; it < 9; it++) {
      size_t gi = gbase + it*256 + t;
      u16x8 v = *(const u16x8*)(yb + gi*8);
      f32x4 o0, o1;
      o0.x = bf2f(v[0])*sc + bi; o0.y = bf2f(v[1])*sc + bi;
      o0.z = bf2f(v[2])*sc + bi; o0.w = bf2f(v[3])*sc + bi;
      o1.x = bf2f(v[4])*sc + bi; o1.y = bf2f(v[5])*sc + bi;
      o1.z = bf2f(v[6])*sc + bi; o1.w = bf2f(v[7])*sc + bi;
      ((f32x4*)out)[gi*2]     = o0;
      ((f32x4*)out)[gi*2 + 1] = o1;
    }
  } else {
    int plane = bid >> 2, q = bid & 3;         // grid 4096, in-place fp32
    int c = plane & 255;
    float s1 = 0.f, s2 = 0.f;
    #pragma unroll
    for (int i = 0; i < NBKT; i++) {
      s1 += wsb[WS_FSUMB + i*256 + c];
      s2 += wsb[WS_FSQB  + i*256 + c];
    }
    float inv = 1.f / (float)NPIX;
    float mu  = s1 * inv;
    float var = s2 * inv - mu*mu;
    float sc  = gf[c] * rsqrtf(var + BN_EPS);
    float bi  = bfv[c] - mu * sc;
    size_t base4 = ((size_t)plane*HW + q*(HW/4)) >> 2;
    #pragma unroll
    for (int it = 0; it < 9; it++) {
      size_t i4 = base4 + it*256 + t;
      f32x4 v = ((f32x4*)out)[i4];
      v.x = v.x*sc + bi; v.y = v.y*sc + bi; v.z = v.z*sc + bi; v.w = v.w*sc + bi;
      ((f32x4*)out)[i4] = v;
    }
  }
}

extern "C" void kernel_launch(void* const* d_in, const int* in_sizes, int n_in,
                              void* d_out, int out_size, void* d_ws, size_t ws_size,
                              hipStream_t stream) {
  const float* x  = (const float*)d_in[0];
  const float* w  = (const float*)d_in[1];
  const float* gs = (const float*)d_in[2];
  const float* bs = (const float*)d_in[3];
  const float* wf = (const float*)d_in[4];
  const float* gf = (const float*)d_in[5];
  const float* bf = (const float*)d_in[6];
  float* y   = (float*)d_out;
  float* wsb = (float*)d_ws;

  bool ybf = ws_size >= (size_t)WS_TOT1 * sizeof(float);

  k_pool   <<<NB*NCH, 192, 0, stream>>>(x, wsb);
  k_wpack  <<<32, 256, 0, stream>>>(wf, wsb);
  k_pyr    <<<NB*POS, 256, 0, stream>>>(w, wsb);
  k_contrib<<<64, 256, 0, stream>>>(wf, gs, bs, wsb);
  if (ybf) k_main<true> <<<NB*576, 256, 0, stream>>>(x, wsb, y);
  else     k_main<false><<<NB*576, 256, 0, stream>>>(x, wsb, y);
  if (ybf) k_norm<true> <<<2048, 256, 0, stream>>>(y, gf, bf, wsb);
  else     k_norm<false><<<4096, 256, 0, stream>>>(y, gf, bf, wsb);
}

// Round 7
// 201.805 us; speedup vs baseline: 1.3450x; 1.0570x over previous
//
#include <hip/hip_runtime.h>

typedef unsigned short u16;
typedef unsigned int   u32;
typedef __attribute__((ext_vector_type(4))) float f32x4;
typedef __attribute__((ext_vector_type(8))) short s16x8;
typedef __attribute__((ext_vector_type(4))) unsigned short u16x4;
typedef __attribute__((ext_vector_type(8))) unsigned short u16x8;

#define HW    36864
#define NCH   256
#define NB    4
#define NPIX  147456
#define POS   85
#define BN_EPS 1e-5f
#define NBKT  16

// ---- workspace float offsets ----
#define WS_PALL    0            // 4*256*85 = 87040
#define WS_YD      87040        // 87040
#define WS_PSUM    174080       // 1024
#define WS_PSQ     175104       // 1024
#define WS_CONTRIB 176128       // 65536 (non-atomic, no zeroing needed)
#define WS_FSUMB   241664       // 4096
#define WS_FSQB    245760       // 4096
#define WS_WPK     249856       // u16[65536] = 32768 floats
#define WS_YBF     282624       // u16 y: 18874368 floats
#define WS_TOT1    (WS_YBF + NB*NCH*HW/2)

__device__ __forceinline__ u16 f2bf(float f) {
  u32 u = __builtin_bit_cast(u32, f);
  u += 0x7fffu + ((u >> 16) & 1u);
  return (u16)(u >> 16);
}
__device__ __forceinline__ float bf2f(u16 h) {
  u32 u = ((u32)h) << 16;
  return __builtin_bit_cast(float, u);
}

// K1: per-(b,c) plane -> 85-entry block-max pyramid (proven round-2 kernel)
__global__ __launch_bounds__(192) void k_pool(const float* __restrict__ x, float* __restrict__ wsb) {
  __shared__ float sm[8][4][48];
  __shared__ float sp[84];
  int bc = blockIdx.x;                       // b*256 + c
  const float* base = x + (size_t)bc * HW;
  int t = threadIdx.x;
  int cg = t % 48, rg = t / 48;
  if (bc == 0) {                             // zero stat accumulators
    for (int i = t; i < 2048; i += 192) wsb[WS_PSUM + i] = 0.f;
    for (int i = t; i < 8192; i += 192) wsb[WS_FSUMB + i] = 0.f;
  }
  #pragma unroll
  for (int byi = 0; byi < 8; byi++) {
    float mm = -3.4e38f;
    #pragma unroll
    for (int rr = 0; rr < 6; rr++) {
      int r = byi*24 + rg + 4*rr;
      f32x4 v = *(const f32x4*)(base + r*192 + cg*4);
      mm = fmaxf(mm, fmaxf(fmaxf(v.x, v.y), fmaxf(v.z, v.w)));
    }
    sm[byi][rg][cg] = mm;
  }
  __syncthreads();
  size_t pb = WS_PALL + (size_t)bc * POS;
  if (t < 64) {
    int by = t >> 3, bx = t & 7;
    float mm = -3.4e38f;
    for (int r2 = 0; r2 < 4; r2++)
      for (int cq = 0; cq < 6; cq++)
        mm = fmaxf(mm, sm[by][r2][bx*6 + cq]);
    sp[t] = mm;
    wsb[pb + t] = mm;
  }
  __syncthreads();
  if (t < 16) {
    int i = t >> 2, j = t & 3;
    float mm = fmaxf(fmaxf(sp[(2*i)*8 + 2*j], sp[(2*i)*8 + 2*j + 1]),
                     fmaxf(sp[(2*i+1)*8 + 2*j], sp[(2*i+1)*8 + 2*j + 1]));
    sp[64 + t] = mm;
    wsb[pb + 64 + t] = mm;
  }
  __syncthreads();
  if (t < 4) {
    int i = t >> 1, j = t & 1;
    float mm = fmaxf(fmaxf(sp[64 + (2*i)*4 + 2*j], sp[64 + (2*i)*4 + 2*j + 1]),
                     fmaxf(sp[64 + (2*i+1)*4 + 2*j], sp[64 + (2*i+1)*4 + 2*j + 1]));
    sp[80 + t] = mm;
    wsb[pb + 80 + t] = mm;
  }
  __syncthreads();
  if (t == 0)
    wsb[pb + 84] = fmaxf(fmaxf(sp[80], sp[81]), fmaxf(sp[82], sp[83]));
}

// K1b: pack wf[:, :256] -> bf16 A-frags wpk[((ks*4+g)*256 + m)*8 + j]
__global__ __launch_bounds__(256) void k_wpack(const float* __restrict__ wf, float* __restrict__ wsb) {
  int fid = blockIdx.x*256 + threadIdx.x;    // 0..8191
  int m = fid & 255, g = (fid >> 8) & 3, ks = fid >> 10;
  const float* src = wf + (size_t)m*1280 + ks*32 + g*8;
  f32x4 a = *(const f32x4*)src;
  f32x4 c = *(const f32x4*)(src + 4);
  u32* dst = (u32*)((u16*)(wsb + WS_WPK) + (size_t)fid*8);
  dst[0] = (u32)f2bf(a.x) | ((u32)f2bf(a.y) << 16);
  dst[1] = (u32)f2bf(a.z) | ((u32)f2bf(a.w) << 16);
  dst[2] = (u32)f2bf(c.x) | ((u32)f2bf(c.y) << 16);
  dst[3] = (u32)f2bf(c.z) | ((u32)f2bf(c.w) << 16);
}

// K2: pyramid convs on distinct block values + BN stat accumulation
__global__ __launch_bounds__(256) void k_pyr(const float* __restrict__ wconv, float* __restrict__ wsb) {
  __shared__ __align__(16) float pv[256];
  int bi = blockIdx.x;                       // b*85 + pos
  int b = bi / 85, pos = bi % 85;
  int d = (pos < 64) ? 3 : (pos < 80) ? 2 : (pos < 84) ? 1 : 0;
  int t = threadIdx.x;
  pv[t] = wsb[WS_PALL + (size_t)(b*NCH + t)*POS + pos];
  __syncthreads();
  const float* wrow = wconv + ((size_t)d*NCH + t)*NCH;
  float acc = 0.f;
  #pragma unroll 4
  for (int c4 = 0; c4 < 64; c4++) {
    f32x4 wv = *(const f32x4*)(wrow + c4*4);
    f32x4 xv = *(const f32x4*)(&pv[c4*4]);
    acc += wv.x*xv.x + wv.y*xv.y + wv.z*xv.z + wv.w*xv.w;
  }
  wsb[WS_YD + (size_t)(b*NCH + t)*POS + pos] = acc;
  atomicAdd(&wsb[WS_PSUM + d*NCH + t], acc);
  atomicAdd(&wsb[WS_PSQ  + d*NCH + t], acc*acc);
}

// K3: contrib[b][o][cell] = sum over all 4 depths (no atomics; grid = 64 cells)
__global__ __launch_bounds__(256) void k_contrib(const float* __restrict__ wf,
                                                 const float* __restrict__ gs,
                                                 const float* __restrict__ bs,
                                                 float* __restrict__ wsb) {
  __shared__ __align__(16) float pn[16][256];   // [d*4+b][c]
  int cell = blockIdx.x;
  int by = cell >> 3, bx = cell & 7;
  int t = threadIdx.x;
  #pragma unroll
  for (int d = 0; d < 4; d++) {
    int pos = (d == 3) ? cell
            : (d == 2) ? 64 + (by >> 1)*4 + (bx >> 1)
            : (d == 1) ? 80 + (by >> 2)*2 + (bx >> 2)
            : 84;
    float cnt = (float)(4 << (2*d));
    float mu  = wsb[WS_PSUM + d*NCH + t] / cnt;
    float var = wsb[WS_PSQ  + d*NCH + t] / cnt - mu*mu;
    float sc  = gs[d*NCH + t] * rsqrtf(var + BN_EPS);
    float bi_ = bs[d*NCH + t] - mu * sc;
    #pragma unroll
    for (int b = 0; b < 4; b++)
      pn[d*4 + b][t] = wsb[WS_YD + (size_t)(b*NCH + t)*POS + pos] * sc + bi_;
  }
  __syncthreads();
  float a0 = 0.f, a1 = 0.f, a2 = 0.f, a3 = 0.f;
  #pragma unroll
  for (int d = 0; d < 4; d++) {
    const float* wrow = wf + (size_t)t*1280 + 256 + d*256;
    #pragma unroll 4
    for (int j = 0; j < 64; j++) {
      f32x4 wv = *(const f32x4*)(wrow + j*4);
      f32x4 p0 = *(const f32x4*)(&pn[d*4 + 0][j*4]);
      f32x4 p1 = *(const f32x4*)(&pn[d*4 + 1][j*4]);
      f32x4 p2 = *(const f32x4*)(&pn[d*4 + 2][j*4]);
      f32x4 p3 = *(const f32x4*)(&pn[d*4 + 3][j*4]);
      a0 += wv.x*p0.x + wv.y*p0.y + wv.z*p0.z + wv.w*p0.w;
      a1 += wv.x*p1.x + wv.y*p1.y + wv.z*p1.z + wv.w*p1.w;
      a2 += wv.x*p2.x + wv.y*p2.y + wv.z*p2.z + wv.w*p2.w;
      a3 += wv.x*p3.x + wv.y*p3.y + wv.z*p3.z + wv.w*p3.w;
    }
  }
  wsb[WS_CONTRIB + (size_t)(0*NCH + t)*64 + cell] = a0;
  wsb[WS_CONTRIB + (size_t)(1*NCH + t)*64 + cell] = a1;
  wsb[WS_CONTRIB + (size_t)(2*NCH + t)*64 + cell] = a2;
  wsb[WS_CONTRIB + (size_t)(3*NCH + t)*64 + cell] = a3;
}

// K4: main GEMM, reg-staged transpose direct from planar fp32 x (r6 loop),
//   NEW epilogue: LDS-bounce retile -> fully coalesced u16x8 y stores.
template<bool YBF>
__global__ __launch_bounds__(256, 3) void k_main(const float* __restrict__ x,
                                                 float* __restrict__ wsb, float* __restrict__ y) {
  __shared__ __align__(16) u32 xbuf[2][64*20];   // [buf][px*20 dw], 80B pitch, 10 KB
  __shared__ float ctile[256*4];                 // 4 KB
  __shared__ __align__(16) u16 ytile[256*72];    // [o][72 px pitch], 36 KB (16B-aligned rows)
  int wg = blockIdx.x;
  int b = wg / 576, tile = wg % 576;
  int n0 = tile * 64;
  int t = threadIdx.x, w = t >> 6, l = t & 63, g = l >> 4, ln = l & 15;
  int cb0 = (tile % 3) * 64;
  int rowblk = (tile / 3) / 24;
  int cblk0 = cb0 / 24;
  const u16* wpk = (const u16*)(wsb + WS_WPK);
  int mrow = w*64 + ln;
  int qq = t & 15, c2 = t >> 4;                  // staging: px-quad, channel-pair
  const float* xsrc = x + (size_t)(b*NCH + 2*c2)*HW + n0 + 4*qq;

  // ctile global loads (issued first)
  float ct[4];
  {
    const float* cbase = wsb + WS_CONTRIB + ((size_t)b*NCH + t)*64 + rowblk*8;
    #pragma unroll
    for (int i = 0; i < 4; i++) {
      int cc = cblk0 + i; if (cc > 7) cc = 7;
      ct[i] = cbase[cc];
    }
  }
  // prologue: x loads slabs 0..3 (8 loads in flight)
  f32x4 xa[4], xbv[4];
  #pragma unroll
  for (int i = 0; i < 4; i++) {
    xa[i]  = *(const f32x4*)(xsrc + (size_t)(i*32)*HW);
    xbv[i] = *(const f32x4*)(xsrc + (size_t)(i*32 + 1)*HW);
  }
  // W-frag double buffer; prefetch slab 0
  s16x8 af[2][4];
  #pragma unroll
  for (int tm = 0; tm < 4; tm++)
    af[0][tm] = *(const s16x8*)(wpk + ((size_t)g*256 + mrow + tm*16)*8);

  #pragma unroll
  for (int i = 0; i < 4; i++) ctile[t*4 + i] = ct[i];
  asm volatile("s_waitcnt lgkmcnt(0)" ::: "memory");
  __builtin_amdgcn_s_barrier();
  __builtin_amdgcn_sched_barrier(0);

  f32x4 acc[4][4];
  #pragma unroll
  for (int i = 0; i < 4; i++)
    #pragma unroll
    for (int j = 0; j < 4; j++)
      acc[i][j] = {0.f, 0.f, 0.f, 0.f};

  int slot = (((c2 >> 2) ^ (qq & 3)) << 2) | (c2 & 3);   // group-XOR swizzle

  #pragma unroll
  for (int i = 0; i < 8; i++) {
    // stage slab i (compiler emits COUNTED vmcnt for xa/xbv[i&3])
    {
      u32* dst = &xbuf[i & 1][0];
      f32x4 va = xa[i & 3], vb = xbv[i & 3];
      #pragma unroll
      for (int j = 0; j < 4; j++) {
        u32 pk = (u32)f2bf(va[j]) | ((u32)f2bf(vb[j]) << 16);
        dst[(4*qq + j)*20 + slot] = pk;
      }
    }
    asm volatile("s_waitcnt lgkmcnt(0)" ::: "memory");
    __builtin_amdgcn_s_barrier();
    __builtin_amdgcn_sched_barrier(0);
    // prefetch x slab i+4
    if (i < 4) {
      xa[i & 3]  = *(const f32x4*)(xsrc + (size_t)((i+4)*32)*HW);
      xbv[i & 3] = *(const f32x4*)(xsrc + (size_t)((i+4)*32 + 1)*HW);
    }
    // prefetch W-frags slab i+1
    if (i < 7) {
      #pragma unroll
      for (int tm = 0; tm < 4; tm++)
        af[(i+1) & 1][tm] = *(const s16x8*)(wpk + ((size_t)((i+1)*4 + g)*256 + mrow + tm*16)*8);
    }
    // compute slab i
    #pragma unroll
    for (int tn = 0; tn < 4; tn++) {
      int px = 16*tn + ln;
      int gr = g ^ ((px >> 2) & 3);
      s16x8 bfr = *(const s16x8*)((const u16*)&xbuf[i & 1][px*20 + gr*4]);
      #pragma unroll
      for (int tm = 0; tm < 4; tm++)
        acc[tm][tn] = __builtin_amdgcn_mfma_f32_16x16x32_bf16(af[i & 1][tm], bfr, acc[tm][tn], 0, 0, 0);
    }
  }

  // epilogue: add contrib, stats, write bf16 into LDS retile
  int ci[4];
  #pragma unroll
  for (int tn = 0; tn < 4; tn++)
    ci[tn] = (cb0 + 16*tn + ln)/24 - cblk0;
  int bkt = wg & (NBKT - 1);
  float* fsum = wsb + WS_FSUMB + bkt*256;
  float* fsq  = wsb + WS_FSQB  + bkt*256;
  float* yf   = y + (size_t)b*NCH*HW + n0;
  #pragma unroll
  for (int tm = 0; tm < 4; tm++) {
    #pragma unroll
    for (int r = 0; r < 4; r++) {
      int o = w*64 + tm*16 + g*4 + r;
      float s1 = 0.f, s2 = 0.f;
      #pragma unroll
      for (int tn = 0; tn < 4; tn++) {
        int px = 16*tn + ln;
        float v = acc[tm][tn][r] + ctile[o*4 + ci[tn]];
        if (YBF) {
          u16 h = f2bf(v);
          ytile[o*72 + px] = h;
          float yr = bf2f(h);
          s1 += yr; s2 += yr*yr;
        } else {
          yf[(size_t)o*HW + px] = v;
          s1 += v; s2 += v*v;
        }
      }
      s1 += __shfl_xor(s1, 1);  s2 += __shfl_xor(s2, 1);
      s1 += __shfl_xor(s1, 2);  s2 += __shfl_xor(s2, 2);
      s1 += __shfl_xor(s1, 4);  s2 += __shfl_xor(s2, 4);
      s1 += __shfl_xor(s1, 8);  s2 += __shfl_xor(s2, 8);
      if (ln == 0) { atomicAdd(&fsum[o], s1); atomicAdd(&fsq[o], s2); }
    }
  }
  if (YBF) {
    __syncthreads();
    // coalesced store: 8 rounds; lane = (o' = t>>3 within 32-o group, seg = t&7)
    u16* ybb = (u16*)(wsb + WS_YBF) + (size_t)b*NCH*HW + n0;
    int oo = t >> 3, seg = t & 7;
    #pragma unroll
    for (int r8 = 0; r8 < 8; r8++) {
      int o = r8*32 + oo;
      u16x8 v = *(const u16x8*)(&ytile[o*72 + seg*8]);
      *(u16x8*)(ybb + (size_t)o*HW + seg*8) = v;
    }
  }
}

// K5: normalize with inline final BN stats (r2-proven coalesced shape)
template<bool YBF>
__global__ __launch_bounds__(256) void k_norm(float* __restrict__ out,
                                              const float* __restrict__ gf,
                                              const float* __restrict__ bfv,
                                              const float* __restrict__ wsb) {
  int bid = blockIdx.x;                      // plane*4 + quarter
  int plane = bid >> 2, q = bid & 3;
  int c = plane & 255;
  float s1 = 0.f, s2 = 0.f;
  #pragma unroll
  for (int i = 0; i < NBKT; i++) {
    s1 += wsb[WS_FSUMB + i*256 + c];
    s2 += wsb[WS_FSQB  + i*256 + c];
  }
  float inv = 1.f / (float)NPIX;
  float mu  = s1 * inv;
  float var = s2 * inv - mu*mu;
  float sc  = gf[c] * rsqrtf(var + BN_EPS);
  float bi  = bfv[c] - mu * sc;
  size_t base4 = ((size_t)plane*HW + q*(HW/4)) >> 2;   // f32x4 / u16x4 index
  int t = threadIdx.x;
  if (YBF) {
    const u16* yb = (const u16*)(wsb + WS_YBF);
    #pragma unroll
    for (int it = 0; it < 9; it++) {
      size_t i4 = base4 + it*256 + t;
      u16x4 v = *(const u16x4*)(yb + i4*4);
      f32x4 o;
      o.x = bf2f(v[0])*sc + bi;
      o.y = bf2f(v[1])*sc + bi;
      o.z = bf2f(v[2])*sc + bi;
      o.w = bf2f(v[3])*sc + bi;
      ((f32x4*)out)[i4] = o;
    }
  } else {
    #pragma unroll
    for (int it = 0; it < 9; it++) {
      size_t i4 = base4 + it*256 + t;
      f32x4 v = ((f32x4*)out)[i4];
      v.x = v.x*sc + bi; v.y = v.y*sc + bi; v.z = v.z*sc + bi; v.w = v.w*sc + bi;
      ((f32x4*)out)[i4] = v;
    }
  }
}

extern "C" void kernel_launch(void* const* d_in, const int* in_sizes, int n_in,
                              void* d_out, int out_size, void* d_ws, size_t ws_size,
                              hipStream_t stream) {
  const float* x  = (const float*)d_in[0];
  const float* w  = (const float*)d_in[1];
  const float* gs = (const float*)d_in[2];
  const float* bs = (const float*)d_in[3];
  const float* wf = (const float*)d_in[4];
  const float* gf = (const float*)d_in[5];
  const float* bf = (const float*)d_in[6];
  float* y   = (float*)d_out;
  float* wsb = (float*)d_ws;

  bool ybf = ws_size >= (size_t)WS_TOT1 * sizeof(float);

  k_pool   <<<NB*NCH, 192, 0, stream>>>(x, wsb);
  k_wpack  <<<32, 256, 0, stream>>>(wf, wsb);
  k_pyr    <<<NB*POS, 256, 0, stream>>>(w, wsb);
  k_contrib<<<64, 256, 0, stream>>>(wf, gs, bs, wsb);
  if (ybf) k_main<true> <<<NB*576, 256, 0, stream>>>(x, wsb, y);
  else     k_main<false><<<NB*576, 256, 0, stream>>>(x, wsb, y);
  if (ybf) k_norm<true> <<<4096, 256, 0, stream>>>(y, gf, bf, wsb);
  else     k_norm<false><<<4096, 256, 0, stream>>>(y, gf, bf, wsb);
}